// Round 4
// baseline (94.410 us; speedup 1.0000x reference)
//
#include <hip/hip_runtime.h>
#include <stdint.h>

#define BATCH 4
#define NN 4096
#define DD 256
#define TI 128
#define TJ 64
#define JS 2
#define JRANGE (NN / JS)      // 2048
#define NITER (JRANGE / TJ)   // 32

#define VS_OFF 0              // 2 x 32768 B (V_j tile [64][256] bf16, 16B-chunk XOR swizzle)
#define VT_OFF 65536          // 2 x 32768 B (V_j^T tile [256][64] bf16, swizzled)
#define P_OFF  131072         // 2 x 16384 B (P [128][64] bf16, swizzled, double-buffered)
#define LDS_BYTES 163840      // exactly 160 KiB

typedef __attribute__((ext_vector_type(8))) short bf16x8;
typedef __attribute__((ext_vector_type(4))) float f32x4;
typedef __attribute__((ext_vector_type(4))) float f4v;
typedef __attribute__((ext_vector_type(8))) short s8v;
typedef __attribute__((ext_vector_type(4))) short s4v;

__device__ __forceinline__ short f2bf(float f) {
    uint32_t u = __builtin_bit_cast(uint32_t, f);
    u = (u + 0x7fffu + ((u >> 16) & 1u)) >> 16;
    return (short)u;
}

__device__ __forceinline__ void g2l16(const void* g, void* l) {
    __builtin_amdgcn_global_load_lds((const __attribute__((address_space(1))) void*)g,
                                     (__attribute__((address_space(3))) void*)l, 16, 0, 0);
}

// ---------------- prep: f32 [B][N][D] -> bf16 [B][N][D] and bf16 [B][D][N] ----------------
__global__ __launch_bounds__(256) void prep_k(const float* __restrict__ val,
                                              short* __restrict__ vbf,
                                              short* __restrict__ vt) {
    __shared__ float tile[32][33];
    int b = blockIdx.z;
    int d0 = blockIdx.x * 32, n0 = blockIdx.y * 32;
    int tx = threadIdx.x, ty = threadIdx.y;
#pragma unroll
    for (int yy = ty; yy < 32; yy += 8) {
        float v = val[((size_t)b * NN + n0 + yy) * DD + d0 + tx];
        tile[yy][tx] = v;
        vbf[((size_t)b * NN + n0 + yy) * DD + d0 + tx] = f2bf(v);
    }
    __syncthreads();
#pragma unroll
    for (int yy = ty; yy < 32; yy += 8)
        vt[((size_t)b * DD + d0 + yy) * NN + n0 + tx] = f2bf(tile[tx][yy]);
}

// ---------------- main fused kernel ----------------
// grid: 256 blocks (XCD-swizzled), 512 threads (8 waves)
// iter t = { stage Vs(t+1) | PV(t-1) | S(t) | softsign(t)->P[t&1] } bar { stage Vt(t+1) }
__global__ void __launch_bounds__(512, 2) prop_main(const short* __restrict__ vbf,
                                                    const short* __restrict__ vtbf,
                                                    const float* __restrict__ state,
                                                    float* __restrict__ part,
                                                    float* __restrict__ spart) {
    extern __shared__ char smem[];

    // XCD-aware swizzle: 32 consecutive blocks (one (b,js) group, shared Vj/Vt
    // stream ~2MB) land on one XCD's L2. 256 % 8 == 0 -> bijective.
    const int raw = blockIdx.x;
    const int bid = ((raw & 7) << 5) | (raw >> 3);
    const int js = (bid >> 5) & 1;
    const int rb = bid & 31;
    const int b = bid >> 6;
    const int tid = threadIdx.x;
    const int w = tid >> 6, lane = tid & 63;
    const int g = lane >> 4, c = lane & 15;
    const int ig = w & 3, jh = w >> 2;
    const int wr = w & 1, wd = w >> 1;
    const int r7 = c & 7;
    const int j0base = js * JRANGE;

    // 16B-slot byte offsets: ((k*4+g)^r7)<<4 = (k>>1)*128 + (k&1 ? xO : xE)
    const int xE = ((((r7 >> 2) << 2) | (g ^ (r7 & 3))) << 4);
    const int xO = (((((r7 >> 2) ^ 1) << 2) | (g ^ (r7 & 3))) << 4);

    // V_i rows resident in registers (B-operand of S^T)
    bf16x8 Bf[2][8];
    const size_t irowb = (size_t)b * NN + rb * TI + ig * 32;
#pragma unroll
    for (int m = 0; m < 2; ++m)
#pragma unroll
        for (int k = 0; k < 8; ++k)
            Bf[m][k] = *(const bf16x8*)(vbf + ((irowb + m * 16 + c) * DD + k * 32 + g * 8));

    f32x4 accO[4][4];
#pragma unroll
    for (int mt = 0; mt < 4; ++mt)
#pragma unroll
        for (int dt = 0; dt < 4; ++dt)
            accO[mt][dt] = (f32x4){0.f, 0.f, 0.f, 0.f};
    float vsum[2] = {0.f, 0.f};

    auto stageVs = [&](int t, int nb) {
        const int j0 = j0base + t * TJ;
        char* dst = smem + VS_OFF + nb * 32768;
#pragma unroll
        for (int p = 0; p < 4; ++p) {
            int ch0 = p * 512 + w * 64;
            int ch = ch0 + lane;
            int row = ch >> 5, cir = ch & 31;
            g2l16(vbf + ((size_t)(b * NN + j0 + row) * DD + ((cir ^ (row & 7)) * 8)),
                  dst + ch0 * 16);
        }
    };
    auto stageVt = [&](int t, int nb) {
        const int j0 = j0base + t * TJ;
        char* dst = smem + VT_OFF + nb * 32768;
#pragma unroll
        for (int p = 0; p < 4; ++p) {
            int ch0 = p * 512 + w * 64;
            int ch = ch0 + lane;
            int d = ch >> 3, cj = ch & 7;
            g2l16(vtbf + ((size_t)(b * DD + d) * NN + j0 + ((cj ^ (d & 7)) * 8)),
                  dst + ch0 * 16);
        }
    };

    auto pvStep = [&](int slot) {
        const char* paRow = smem + P_OFF + slot * 16384 + (wr * 64 + c) * 128;
        const char* vbRow = smem + VT_OFF + slot * 32768 + (wd * 64 + c) * 128;
        __builtin_amdgcn_s_setprio(1);
#pragma unroll
        for (int kk = 0; kk < 2; ++kk) {
            const int off = kk ? xO : xE;
            bf16x8 pa[4], vb[4];
#pragma unroll
            for (int mt = 0; mt < 4; ++mt) pa[mt] = *(const bf16x8*)(paRow + mt * 2048 + off);
#pragma unroll
            for (int dt = 0; dt < 4; ++dt) vb[dt] = *(const bf16x8*)(vbRow + dt * 2048 + off);
#pragma unroll
            for (int mt = 0; mt < 4; ++mt)
#pragma unroll
                for (int dt = 0; dt < 4; ++dt)
                    accO[mt][dt] = __builtin_amdgcn_mfma_f32_16x16x32_bf16(pa[mt], vb[dt], accO[mt][dt], 0, 0, 0);
        }
        __builtin_amdgcn_s_setprio(0);
    };

    const float* stp = state + b * NN + j0base;

    // prologue: tile 0 into slot 0
    stageVs(0, 0);
    stageVt(0, 0);
    __syncthreads();

    for (int t = 0; t < NITER; ++t) {
        const int cur = t & 1, prv = cur ^ 1;

        // issue next Vs stage first (2-slot alternation; reader finished last iter)
        if (t + 1 < NITER) stageVs(t + 1, prv);

        // state prefetch for this tile (L2-resident broadcast)
        f4v sv0 = *(const f4v*)(stp + t * TJ + jh * 32 + g * 4);
        f4v sv1 = *(const f4v*)(stp + t * TJ + jh * 32 + 16 + g * 4);

        // ---- PV(t-1): O += P . V_j  (reads P[prv], Vt[prv]; ready since last barrier) ----
        if (t > 0) pvStep(prv);

        // ---- S(t): S^T = V_j . V_i^T  (A = V_j from Vs[cur], B = V_i regs) ----
        f32x4 accS[2][2];
#pragma unroll
        for (int jbl = 0; jbl < 2; ++jbl)
#pragma unroll
            for (int m = 0; m < 2; ++m)
                accS[jbl][m] = (f32x4){0.f, 0.f, 0.f, 0.f};

        const char* aRow0 = smem + VS_OFF + cur * 32768 + (jh * 32 + c) * 512;
        __builtin_amdgcn_s_setprio(1);
#pragma unroll
        for (int k = 0; k < 8; ++k) {
            const int off = (k >> 1) * 128 + ((k & 1) ? xO : xE);
            bf16x8 a0 = *(const bf16x8*)(aRow0 + off);
            bf16x8 a1 = *(const bf16x8*)(aRow0 + 8192 + off);
            accS[0][0] = __builtin_amdgcn_mfma_f32_16x16x32_bf16(a0, Bf[0][k], accS[0][0], 0, 0, 0);
            accS[0][1] = __builtin_amdgcn_mfma_f32_16x16x32_bf16(a0, Bf[1][k], accS[0][1], 0, 0, 0);
            accS[1][0] = __builtin_amdgcn_mfma_f32_16x16x32_bf16(a1, Bf[0][k], accS[1][0], 0, 0, 0);
            accS[1][1] = __builtin_amdgcn_mfma_f32_16x16x32_bf16(a1, Bf[1][k], accS[1][1], 0, 0, 0);
        }
        __builtin_amdgcn_s_setprio(0);

        // ---- softsign(t) + state-accum + packed P write into P[cur] ----
#pragma unroll
        for (int jbl = 0; jbl < 2; ++jbl) {
            f4v sv = jbl ? sv1 : sv0;
#pragma unroll
            for (int m = 0; m < 2; ++m) {
                s4v pk;
#pragma unroll
                for (int r = 0; r < 4; ++r) {
                    float s = accS[jbl][m][r];
                    float e = s * __builtin_amdgcn_rcpf(1.0f + __builtin_fabsf(s));
                    vsum[m] += e * sv[r];
                    pk[r] = f2bf(e);
                }
                int i = ig * 32 + m * 16 + c;
                *(s4v*)(smem + P_OFF + cur * 16384 + i * 128 +
                        ((jh * 64 + jbl * 32 + g * 8) ^ (r7 << 4))) = pk;
            }
        }

        __syncthreads();   // P[cur] visible; Vs(t+1) + Vt(t+1)-from-prev-iter drained

        if (t + 1 < NITER) stageVt(t + 1, prv);
    }

    // epilogue: PV for the last tile
    pvStep((NITER - 1) & 1);

    // ---- delta_val partials ----
    {
        float* po = part + (((size_t)(js * BATCH + b) * NN + rb * TI + wr * 64) * DD) + wd * 64;
#pragma unroll
        for (int mt = 0; mt < 4; ++mt)
#pragma unroll
            for (int dt = 0; dt < 4; ++dt)
#pragma unroll
                for (int r = 0; r < 4; ++r)
                    po[(size_t)(mt * 16 + g * 4 + r) * DD + dt * 16 + c] = accO[mt][dt][r];
    }

    // ---- delta_state partials (reduce over g via shfl, across jh via LDS) ----
#pragma unroll
    for (int m = 0; m < 2; ++m) {
        vsum[m] += __shfl_xor(vsum[m], 16);
        vsum[m] += __shfl_xor(vsum[m], 32);
    }
    float* Xf = (float*)(smem + P_OFF);   // P[0] region is dead now
    __syncthreads();
    if (jh == 1 && lane < 16) {
        Xf[(ig * 2 + 0) * 16 + lane] = vsum[0];
        Xf[(ig * 2 + 1) * 16 + lane] = vsum[1];
    }
    __syncthreads();
    if (jh == 0 && lane < 16) {
        size_t sb = ((size_t)js * BATCH + b) * NN + rb * TI + ig * 32;
#pragma unroll
        for (int m = 0; m < 2; ++m)
            spart[sb + m * 16 + lane] = vsum[m] + Xf[(ig * 2 + m) * 16 + lane];
    }
}

// ---------------- final reduce: out[b,i,0:256] = p0+p1 ; out[b,i,256] = s0+s1 ----------------
__global__ __launch_bounds__(256) void reduce2_k(const float* __restrict__ part,
                                                 const float* __restrict__ spart,
                                                 float* __restrict__ out) {
    const int row = blockIdx.x;           // b*4096 + i
    const int t = threadIdx.x;
    const size_t PS = (size_t)BATCH * NN * DD;
    float v = part[(size_t)row * DD + t] + part[PS + (size_t)row * DD + t];
    out[(size_t)row * 257 + t] = v;
    if (t == 0) {
        const size_t SS = (size_t)BATCH * NN;
        out[(size_t)row * 257 + 256] = spart[row] + spart[SS + row];
    }
}

extern "C" void kernel_launch(void* const* d_in, const int* in_sizes, int n_in,
                              void* d_out, int out_size, void* d_ws, size_t ws_size,
                              hipStream_t stream) {
    const float* val = (const float*)d_in[0];
    const float* state = (const float*)d_in[1];
    float* out = (float*)d_out;

    const size_t bf_bytes = (size_t)BATCH * NN * DD * 2;          // 8 MiB
    const size_t part_bytes = (size_t)JS * BATCH * NN * DD * 4;   // 32 MiB
    const size_t spart_bytes = (size_t)JS * BATCH * NN * 4;       // 128 KiB
    short* vbf = (short*)d_ws;
    short* vtbf = (short*)((char*)d_ws + bf_bytes);
    float* part = (float*)((char*)d_ws + 2 * bf_bytes);
    float* spart = (float*)((char*)d_ws + 2 * bf_bytes + part_bytes);
    if (ws_size < 2 * bf_bytes + part_bytes + spart_bytes) return;

    hipFuncSetAttribute((const void*)prop_main, hipFuncAttributeMaxDynamicSharedMemorySize, LDS_BYTES);

    prep_k<<<dim3(DD / 32, NN / 32, BATCH), dim3(32, 8), 0, stream>>>(val, vbf, vtbf);
    prop_main<<<BATCH * (NN / TI) * JS, 512, LDS_BYTES, stream>>>(vbf, vtbf, state, part, spart);
    reduce2_k<<<BATCH * NN, 256, 0, stream>>>(part, spart, out);
}